// Round 26
// baseline (160.287 us; speedup 1.0000x reference)
//
#include <hip/hip_runtime.h>
#include <float.h>

// Sparsemax attention v18 = r25 + collect@THR_A folded into pass 1:
// 1-scan common path.  B=2,H=16,S=2048,D=64 fp32, temperature 8.
//
// Exact tier check (any data): G(21) >= 8 <=> 21 <= tau*. When tier A is
// valid, {s > 21} is a provable superset of the support -> the capped
// collect done during pass 1 is already the candidate list, and Michelot
// runs from t1 = 21 + (G-8)/C. Whole wave tier-A-valid + no cap overflow
// (dominant case) -> pass 2 SKIPPED: one K-scan total.
// Otherwise: r25 verbatim (per-row t1 from tier B / safety scan @(max-8),
// recollect@t1 -> t2, list Michelot; cap overflow -> full-scan Michelot +
// dense PV). Correct for any data.

#define S_LEN 2048
#define DHEAD 64
#define WROWS 16
#define BWAVES 4
#define LCAP 32
#define THR_A 21.0f
#define THR_B 16.0f

typedef _Float16 f16x8 __attribute__((ext_vector_type(8)));
typedef __attribute__((ext_vector_type(4))) float f32x4;

__device__ __forceinline__ unsigned short f2h(float x) {
    return __builtin_bit_cast(unsigned short, (_Float16)x);
}
__device__ __forceinline__ unsigned int pk2h(float lo, float hi) {
    return (unsigned int)f2h(lo) | ((unsigned int)f2h(hi) << 16);
}
__device__ __forceinline__ f16x8 cvt8h(float4 a, float4 b) {
    union { unsigned int u[4]; f16x8 v; } r;
    r.u[0] = pk2h(a.x, a.y); r.u[1] = pk2h(a.z, a.w);
    r.u[2] = pk2h(b.x, b.y); r.u[3] = pk2h(b.z, b.w);
    return r.v;
}

// K fp32 [bh][2048][64] -> fragment-contiguous fp16 (r14-proven layout).
__global__ __launch_bounds__(256)
void kswz_kernel(const float* __restrict__ K, uint4* __restrict__ dst, int nfrag) {
    int tid = blockIdx.x * 256 + threadIdx.x;
    if (tid >= nfrag) return;
    const int lane = tid & 63;
    const int grp  = (tid >> 6) & 1;
    const int ct   = (tid >> 7) & 127;
    const int bh   = tid >> 14;
    const int row  = ct * 16 + (lane & 15);
    const int col  = grp * 32 + (lane >> 4) * 8;
    const float* src = K + ((size_t)bh * S_LEN + row) * DHEAD + col;
    float4 a = *reinterpret_cast<const float4*>(src);
    float4 b = *reinterpret_cast<const float4*>(src + 4);
    uint4 o;
    o.x = pk2h(a.x, a.y); o.y = pk2h(a.z, a.w);
    o.z = pk2h(b.x, b.y); o.w = pk2h(b.z, b.w);
    dst[tid] = o;
}

__global__ __launch_bounds__(256, 4)
void spx_main(const float* __restrict__ Q,
              const unsigned short* __restrict__ Ks,
              const float* __restrict__ V,
              float* __restrict__ O)
{
    // [wave][slot][lane]; wave's 8 KB chunk doubles as fallback p-buffer.
    __shared__ unsigned int s_pack[BWAVES][LCAP][64];   // 32 KB

    const int t    = threadIdx.x;
    const int widx = t >> 6;
    const int l    = t & 63;
    const int lm   = l & 15;
    const int lk   = l >> 4;

    int bid = blockIdx.x;
    if (((int)gridDim.x & 7) == 0)
        bid = (bid & 7) * ((int)gridDim.x >> 3) + (bid >> 3);   // XCD swizzle
    const int nrb   = S_LEN / (WROWS * BWAVES);      // 32 row-blocks per bh
    const int bh    = bid / nrb;
    const int row0w = (bid % nrb) * (WROWS * BWAVES) + widx * WROWS;

    const float* Qf = Q + (size_t)bh * S_LEN * DHEAD;
    const unsigned short* KsB = Ks + (size_t)bh * S_LEN * DHEAD;
    const float* Vb = V + (size_t)bh * S_LEN * DHEAD;
    float* Of = O + (size_t)bh * S_LEN * DHEAD;

    // ---- Q^T B-fragments ----
    f16x8 qfrag[2];
    #pragma unroll
    for (int kp = 0; kp < 2; ++kp) {
        const float* qp = Qf + (size_t)(row0w + lm) * DHEAD + kp * 32 + lk * 8;
        qfrag[kp] = cvt8h(*reinterpret_cast<const float4*>(qp),
                          *reinterpret_cast<const float4*>(qp + 4));
    }

    // transient score tile: S[qrow=lm][ct*16 + lk*4 + e], contiguous frags
    #define SCORE_TILE(a_, ct_)                                                  \
        {                                                                        \
            const unsigned short* kb_ = KsB + (size_t)(ct_) * 1024;              \
            f16x8 k0_ = *reinterpret_cast<const f16x8*>(kb_ + l * 8);            \
            f16x8 k1_ = *reinterpret_cast<const f16x8*>(kb_ + 512 + l * 8);      \
            a_ = (f32x4){0.f, 0.f, 0.f, 0.f};                                    \
            a_ = __builtin_amdgcn_mfma_f32_16x16x32_f16(k0_, qfrag[0], a_, 0, 0, 0); \
            a_ = __builtin_amdgcn_mfma_f32_16x16x32_f16(k1_, qfrag[1], a_, 0, 0, 0); \
        }

    // ---- pass 1: rowmax + g-probes {21,16} + capped collect @ THR_A ----
    float mx = -FLT_MAX;
    float gA = 0.f, cA = 0.f, gB = 0.f, cB = 0.f;
    int own = 0;
    #pragma unroll 2
    for (int ct = 0; ct < S_LEN / 16; ++ct) {
        f32x4 a;
        SCORE_TILE(a, ct);
        #pragma unroll
        for (int e = 0; e < 4; ++e) {
            const float v = a[e];
            mx = fmaxf(mx, v);
            const float dA = v - THR_A;
            const float dB = v - THR_B;
            gA += fmaxf(dA, 0.f);
            gB += fmaxf(dB, 0.f);
            cB += (dB > 0.f) ? 1.f : 0.f;
            if (dA > 0.f) {
                cA += 1.f;
                if (own < LCAP) {
                    const unsigned int pk =
                        (__builtin_bit_cast(unsigned int, v) & 0xFFFFF800u)
                        | (unsigned int)(ct * 16 + lk * 4 + e);
                    s_pack[widx][own][l] = pk;
                }
                ++own;
            }
        }
    }
    for (int i = (own < LCAP ? own : LCAP); i < LCAP; ++i)
        s_pack[widx][i][l] = 0xFF800000u;         // -inf sentinel, col 0
    mx = fmaxf(mx, __shfl_xor(mx, 16));
    mx = fmaxf(mx, __shfl_xor(mx, 32));
    gA += __shfl_xor(gA, 16); gA += __shfl_xor(gA, 32);
    cA += __shfl_xor(cA, 16); cA += __shfl_xor(cA, 32);
    gB += __shfl_xor(gB, 16); gB += __shfl_xor(gB, 32);
    cB += __shfl_xor(cB, 16); cB += __shfl_xor(cB, 32);

    // fast path: whole wave tier-A-valid (21 <= tau* for all rows, EXACT)
    // and no lane cap overflow -> pass-1 list is a support superset.
    const bool fast = __all((gA >= 8.f) ? 1 : 0) && !__any(own > LCAP);

    float startT;
    bool ovf;
    if (fast) {
        startT = THR_A + (gA - 8.f) / cA;         // exact iterate in [21,tau*]
        ovf = false;
    } else {
        // ---- r25 slow path: per-row t1 from tiers / safety scan ----
        float t1;
        bool rowvalid;
        if (gA >= 8.f)      { t1 = THR_A + (gA - 8.f) / cA; rowvalid = true; }
        else if (gB >= 8.f) { t1 = THR_B + (gB - 8.f) / cB; rowvalid = true; }
        else                { t1 = mx - 8.f;               rowvalid = false; }

        if (!__all(rowvalid ? 1 : 0)) {
            // safety: capless (sum,count)@(max-8) -> exact iterate (any data)
            const float thr0 = mx - 8.f;
            float s2 = 0.f, c2 = 0.f;
            #pragma unroll 4
            for (int ct = 0; ct < S_LEN / 16; ++ct) {
                f32x4 a;
                SCORE_TILE(a, ct);
                #pragma unroll
                for (int e = 0; e < 4; ++e) {
                    const bool in = a[e] > thr0;
                    s2 += in ? a[e] : 0.f;
                    c2 += in ? 1.f : 0.f;
                }
            }
            s2 += __shfl_xor(s2, 16); c2 += __shfl_xor(c2, 16);
            s2 += __shfl_xor(s2, 32); c2 += __shfl_xor(c2, 32);
            t1 = (s2 - 8.f) / c2;
        }

        // pass 2: recollect {s > t1} + capless (sum,count)@t1 -> t2
        own = 0;
        float s3 = 0.f, c3 = 0.f;
        #pragma unroll 2
        for (int ct = 0; ct < S_LEN / 16; ++ct) {
            f32x4 a;
            SCORE_TILE(a, ct);
            #pragma unroll
            for (int e = 0; e < 4; ++e) {
                const float v = a[e];
                if (v > t1) {
                    s3 += v; c3 += 1.f;
                    if (own < LCAP) {
                        const unsigned int pk =
                            (__builtin_bit_cast(unsigned int, v) & 0xFFFFF800u)
                            | (unsigned int)(ct * 16 + lk * 4 + e);
                        s_pack[widx][own][l] = pk;
                    }
                    ++own;
                }
            }
        }
        for (int i = (own < LCAP ? own : LCAP); i < LCAP; ++i)
            s_pack[widx][i][l] = 0xFF800000u;
        s3 += __shfl_xor(s3, 16); c3 += __shfl_xor(c3, 16);
        s3 += __shfl_xor(s3, 32); c3 += __shfl_xor(c3, 32);
        startT = (s3 - 8.f) / c3;                 // t2, exact
        ovf = __any(own > LCAP);
    }

    // wave-wide max slot count (bounds the PV loop)
    int maxc = own < LCAP ? own : LCAP;
    #pragma unroll
    for (int o = 1; o < 64; o <<= 1) {
        const int m2 = __shfl_xor(maxc, o);
        maxc = m2 > maxc ? m2 : maxc;
    }

    float tauF;
    if (!ovf) {
        // ---- in-wave list Michelot from startT (1-2 steps to fixpoint) ----
        float cand[LCAP];
        #pragma unroll
        for (int s = 0; s < LCAP; ++s)
            cand[s] = __builtin_bit_cast(float, s_pack[widx][s][l] & 0xFFFFF800u);
        float tv = startT;
        int cprev = -1;
        for (int it = 0; it < 20; ++it) {
            float s = 0.f, c = 0.f;
            #pragma unroll
            for (int q = 0; q < LCAP; ++q) {
                const bool in = cand[q] > tv;
                s += in ? cand[q] : 0.f;
                c += in ? 1.f : 0.f;
            }
            s += __shfl_xor(s, 16); c += __shfl_xor(c, 16);
            s += __shfl_xor(s, 32); c += __shfl_xor(c, 32);
            tv = (s - 8.f) / c;
            const int C = (int)c;
            const bool done = (C == cprev);
            cprev = C;
            if (__all(done ? 1 : 0)) break;   // fixpoint on all rows: exact
        }
        tauF = tv;

        // ---- branchless interleaved sparse PV (r17/r18-proven) ----
        float tr[WROWS];
        #pragma unroll
        for (int r = 0; r < WROWS; ++r) tr[r] = __shfl(tauF, r);
        float oac[WROWS];
        #pragma unroll
        for (int r = 0; r < WROWS; ++r) oac[r] = 0.f;
        const float* Vl = Vb + l;

        for (int i = 0; i < maxc; ++i) {
            #pragma unroll
            for (int r = 0; r < WROWS; ++r) {
                #pragma unroll
                for (int j = 0; j < 4; ++j) {
                    const unsigned int pk = s_pack[widx][i][r + 16 * j]; // bcast
                    const float val =
                        __builtin_bit_cast(float, pk & 0xFFFFF800u);
                    const float pp = fmaxf(val - tr[r], 0.f);  // 0 for sentinel
                    const int col = (int)(pk & 0x7FFu);
                    oac[r] = fmaf(pp, Vl[(size_t)col * DHEAD], oac[r]);
                }
            }
        }
        #pragma unroll
        for (int r = 0; r < WROWS; ++r)
            Of[(size_t)(row0w + r) * DHEAD + l] = oac[r] * 0.125f;
    } else {
        // ---- fallback: full-scan Michelot from startT + dense PV ----
        float tv = startT;
        int cprev = -1;
        for (int it = 0; it < 12; ++it) {
            float s = 0.f, c = 0.f;
            #pragma unroll 4
            for (int ct = 0; ct < S_LEN / 16; ++ct) {
                f32x4 a;
                SCORE_TILE(a, ct);
                #pragma unroll
                for (int e = 0; e < 4; ++e) {
                    const bool in = a[e] > tv;
                    s += in ? a[e] : 0.f;
                    c += in ? 1.f : 0.f;
                }
            }
            s += __shfl_xor(s, 16); c += __shfl_xor(c, 16);
            s += __shfl_xor(s, 32); c += __shfl_xor(c, 32);
            tv = (s - 8.f) / c;
            const int C = (int)c;
            const bool done = (C == cprev);
            cprev = C;
            if (__all(done ? 1 : 0)) break;
        }
        tauF = tv;

        // dense chunked PV via this wave's own 8 KB LDS chunk as [16][128]
        float* p_lds = reinterpret_cast<float*>(&s_pack[widx][0][0]);
        float ofb[WROWS];
        #pragma unroll
        for (int r = 0; r < WROWS; ++r) ofb[r] = 0.f;
        for (int cc = 0; cc < 16; ++cc) {
            #pragma unroll
            for (int tt = 0; tt < 8; ++tt) {
                f32x4 a;
                SCORE_TILE(a, cc * 8 + tt);
                #pragma unroll
                for (int e = 0; e < 4; ++e)
                    p_lds[lm * 128 + tt * 16 + lk * 4 + e] = fmaxf(a[e] - tauF, 0.f);
            }
            for (int c2 = 0; c2 < 128; ++c2) {
                const float vv = Vb[(size_t)(cc * 128 + c2) * DHEAD + l];
                #pragma unroll
                for (int r = 0; r < WROWS; ++r)
                    ofb[r] += p_lds[r * 128 + c2] * vv;
            }
        }
        #pragma unroll
        for (int r = 0; r < WROWS; ++r)
            Of[(size_t)(row0w + r) * DHEAD + l] = ofb[r] * 0.125f;
    }
    #undef SCORE_TILE
}

extern "C" void kernel_launch(void* const* d_in, const int* in_sizes, int n_in,
                              void* d_out, int out_size, void* d_ws, size_t ws_size,
                              hipStream_t stream) {
    const float* q = (const float*)d_in[0];
    const float* k = (const float*)d_in[1];
    const float* v = (const float*)d_in[2];
    float* out = (float*)d_out;

    const int nElem = in_sizes[0];                    // B*H*S*D = 4194304
    const int BH    = nElem / (S_LEN * DHEAD);

    unsigned short* ks = (unsigned short*)d_ws;
    const int nfrag = nElem / 8;
    kswz_kernel<<<(nfrag + 255) / 256, 256, 0, stream>>>(k, (uint4*)ks, nfrag);

    const int grid = BH * (S_LEN / (WROWS * BWAVES)); // 1024 blocks
    spx_main<<<grid, 256, 0, stream>>>(q, ks, v, out);
}

// Round 27
// 141.323 us; speedup vs baseline: 1.1342x; 1.1342x over previous
//
#include <hip/hip_runtime.h>
#include <float.h>

// Sparsemax attention v19 = r25 (champion, 144us) + occupancy/VALU trims:
//   - LCAP 32->24: LDS 32->24 KB -> 6 blocks/CU (24 waves) vs 4 (16).
//   - pass 2 drops the capless (s,c) accumulate; Michelot starts from t1
//     (one extra cheap in-register iteration instead of 25% of scan-2 VALU).
//   - fallback dense PV chunked at 64 cols (fits the 6 KB wave chunk).
// B=2,H=16,S=2048,D=64 fp32, temperature 8.
//
//   pass 1: rowmax + g-probes G/C @ {21,16} -> per-row exact iterate t1
//           (G(thr)>=8 <=> thr<=tau*, exact for any data).
//   pass 2: collect {s > t1} (capped, sentinel-padded).
//   list Michelot from t1 -> exact tau; branchless interleaved sparse PV.
// Safety: no valid tier -> capless (s,c)@(max-8) scan for t1;
// cap overflow -> full-scan Michelot from t1 + dense PV. Any-data correct.

#define S_LEN 2048
#define DHEAD 64
#define WROWS 16
#define BWAVES 4
#define LCAP 24
#define THR_A 21.0f
#define THR_B 16.0f

typedef _Float16 f16x8 __attribute__((ext_vector_type(8)));
typedef __attribute__((ext_vector_type(4))) float f32x4;

__device__ __forceinline__ unsigned short f2h(float x) {
    return __builtin_bit_cast(unsigned short, (_Float16)x);
}
__device__ __forceinline__ unsigned int pk2h(float lo, float hi) {
    return (unsigned int)f2h(lo) | ((unsigned int)f2h(hi) << 16);
}
__device__ __forceinline__ f16x8 cvt8h(float4 a, float4 b) {
    union { unsigned int u[4]; f16x8 v; } r;
    r.u[0] = pk2h(a.x, a.y); r.u[1] = pk2h(a.z, a.w);
    r.u[2] = pk2h(b.x, b.y); r.u[3] = pk2h(b.z, b.w);
    return r.v;
}

// K fp32 [bh][2048][64] -> fragment-contiguous fp16 (r14-proven layout).
__global__ __launch_bounds__(256)
void kswz_kernel(const float* __restrict__ K, uint4* __restrict__ dst, int nfrag) {
    int tid = blockIdx.x * 256 + threadIdx.x;
    if (tid >= nfrag) return;
    const int lane = tid & 63;
    const int grp  = (tid >> 6) & 1;
    const int ct   = (tid >> 7) & 127;
    const int bh   = tid >> 14;
    const int row  = ct * 16 + (lane & 15);
    const int col  = grp * 32 + (lane >> 4) * 8;
    const float* src = K + ((size_t)bh * S_LEN + row) * DHEAD + col;
    float4 a = *reinterpret_cast<const float4*>(src);
    float4 b = *reinterpret_cast<const float4*>(src + 4);
    uint4 o;
    o.x = pk2h(a.x, a.y); o.y = pk2h(a.z, a.w);
    o.z = pk2h(b.x, b.y); o.w = pk2h(b.z, b.w);
    dst[tid] = o;
}

__global__ __launch_bounds__(256, 4)
void spx_main(const float* __restrict__ Q,
              const unsigned short* __restrict__ Ks,
              const float* __restrict__ V,
              float* __restrict__ O)
{
    // [wave][slot][lane] = 24 KB; wave's 6 KB chunk doubles as the
    // fallback p-buffer [16][64] (4 KB needed).
    __shared__ unsigned int s_pack[BWAVES][LCAP][64];

    const int t    = threadIdx.x;
    const int widx = t >> 6;
    const int l    = t & 63;
    const int lm   = l & 15;
    const int lk   = l >> 4;

    int bid = blockIdx.x;
    if (((int)gridDim.x & 7) == 0)
        bid = (bid & 7) * ((int)gridDim.x >> 3) + (bid >> 3);   // XCD swizzle
    const int nrb   = S_LEN / (WROWS * BWAVES);      // 32 row-blocks per bh
    const int bh    = bid / nrb;
    const int row0w = (bid % nrb) * (WROWS * BWAVES) + widx * WROWS;

    const float* Qf = Q + (size_t)bh * S_LEN * DHEAD;
    const unsigned short* KsB = Ks + (size_t)bh * S_LEN * DHEAD;
    const float* Vb = V + (size_t)bh * S_LEN * DHEAD;
    float* Of = O + (size_t)bh * S_LEN * DHEAD;

    // ---- Q^T B-fragments ----
    f16x8 qfrag[2];
    #pragma unroll
    for (int kp = 0; kp < 2; ++kp) {
        const float* qp = Qf + (size_t)(row0w + lm) * DHEAD + kp * 32 + lk * 8;
        qfrag[kp] = cvt8h(*reinterpret_cast<const float4*>(qp),
                          *reinterpret_cast<const float4*>(qp + 4));
    }

    // transient score tile: S[qrow=lm][ct*16 + lk*4 + e], contiguous frags
    #define SCORE_TILE(a_, ct_)                                                  \
        {                                                                        \
            const unsigned short* kb_ = KsB + (size_t)(ct_) * 1024;              \
            f16x8 k0_ = *reinterpret_cast<const f16x8*>(kb_ + l * 8);            \
            f16x8 k1_ = *reinterpret_cast<const f16x8*>(kb_ + 512 + l * 8);      \
            a_ = (f32x4){0.f, 0.f, 0.f, 0.f};                                    \
            a_ = __builtin_amdgcn_mfma_f32_16x16x32_f16(k0_, qfrag[0], a_, 0, 0, 0); \
            a_ = __builtin_amdgcn_mfma_f32_16x16x32_f16(k1_, qfrag[1], a_, 0, 0, 0); \
        }

    // ---- pass 1: row max + g-probes at fixed thresholds {21, 16} ----
    float mx = -FLT_MAX;
    float gA = 0.f, cA = 0.f, gB = 0.f, cB = 0.f;
    #pragma unroll 4
    for (int ct = 0; ct < S_LEN / 16; ++ct) {
        f32x4 a;
        SCORE_TILE(a, ct);
        #pragma unroll
        for (int e = 0; e < 4; ++e) {
            const float v = a[e];
            mx = fmaxf(mx, v);
            const float dA = v - THR_A;
            const float dB = v - THR_B;
            gA += fmaxf(dA, 0.f);
            gB += fmaxf(dB, 0.f);
            cA += (dA > 0.f) ? 1.f : 0.f;
            cB += (dB > 0.f) ? 1.f : 0.f;
        }
    }
    mx = fmaxf(mx, __shfl_xor(mx, 16));
    mx = fmaxf(mx, __shfl_xor(mx, 32));
    gA += __shfl_xor(gA, 16); gA += __shfl_xor(gA, 32);
    cA += __shfl_xor(cA, 16); cA += __shfl_xor(cA, 32);
    gB += __shfl_xor(gB, 16); gB += __shfl_xor(gB, 32);
    cB += __shfl_xor(cB, 16); cB += __shfl_xor(cB, 32);

    // per-row start: highest valid tier's exact Michelot iterate
    // validity: G(thr) >= 8  <=>  thr <= tau*   (exact, any data)
    float t1;
    bool rowvalid;
    if (gA >= 8.f) {
        t1 = THR_A + (gA - 8.f) / cA;
        rowvalid = true;
    } else if (gB >= 8.f) {
        t1 = THR_B + (gB - 8.f) / cB;
        rowvalid = true;
    } else {
        t1 = mx - 8.f;                  // placeholder; refined below
        rowvalid = false;
    }

    if (!__all(rowvalid ? 1 : 0)) {
        // ---- safety scan (any-data correctness; ~never for Gaussian):
        //      capless (sum,count)@(max-8) -> exact iterate, all rows ----
        const float thr0 = mx - 8.f;
        float s2 = 0.f, c2 = 0.f;
        #pragma unroll 4
        for (int ct = 0; ct < S_LEN / 16; ++ct) {
            f32x4 a;
            SCORE_TILE(a, ct);
            #pragma unroll
            for (int e = 0; e < 4; ++e) {
                const bool in = a[e] > thr0;
                s2 += in ? a[e] : 0.f;
                c2 += in ? 1.f : 0.f;
            }
        }
        s2 += __shfl_xor(s2, 16); c2 += __shfl_xor(c2, 16);
        s2 += __shfl_xor(s2, 32); c2 += __shfl_xor(c2, 32);
        t1 = (s2 - 8.f) / c2;           // exact iterate; c2 >= 1
    }

    // ---- pass 2: collect {s > t1} (capped, sentinel-padded) ----
    int own = 0;
    #pragma unroll 2
    for (int ct = 0; ct < S_LEN / 16; ++ct) {
        f32x4 a;
        SCORE_TILE(a, ct);
        #pragma unroll
        for (int e = 0; e < 4; ++e) {
            const float v = a[e];
            if (v > t1) {
                if (own < LCAP) {
                    const unsigned int pk =
                        (__builtin_bit_cast(unsigned int, v) & 0xFFFFF800u)
                        | (unsigned int)(ct * 16 + lk * 4 + e);
                    s_pack[widx][own][l] = pk;
                }
                ++own;
            }
        }
    }
    for (int i = (own < LCAP ? own : LCAP); i < LCAP; ++i)
        s_pack[widx][i][l] = 0xFF800000u;         // -inf sentinel, col 0

    // wave-wide max slot count (bounds the PV loop)
    int maxc = own < LCAP ? own : LCAP;
    #pragma unroll
    for (int o = 1; o < 64; o <<= 1) {
        const int m2 = __shfl_xor(maxc, o);
        maxc = m2 > maxc ? m2 : maxc;
    }

    const bool ovf = __any(own > LCAP);
    float tauF;
    if (!ovf) {
        // ---- in-wave list Michelot from t1 (2-3 steps to fixpoint) ----
        float cand[LCAP];
        #pragma unroll
        for (int s = 0; s < LCAP; ++s)
            cand[s] = __builtin_bit_cast(float, s_pack[widx][s][l] & 0xFFFFF800u);
        float tv = t1;
        int cprev = -1;
        for (int it = 0; it < 20; ++it) {
            float s = 0.f, c = 0.f;
            #pragma unroll
            for (int q = 0; q < LCAP; ++q) {
                const bool in = cand[q] > tv;
                s += in ? cand[q] : 0.f;
                c += in ? 1.f : 0.f;
            }
            s += __shfl_xor(s, 16); c += __shfl_xor(c, 16);
            s += __shfl_xor(s, 32); c += __shfl_xor(c, 32);
            tv = (s - 8.f) / c;
            const int C = (int)c;
            const bool done = (C == cprev);
            cprev = C;
            if (__all(done ? 1 : 0)) break;   // fixpoint on all rows: exact
        }
        tauF = tv;

        // ---- branchless interleaved sparse PV (r17/r18-proven) ----
        float tr[WROWS];
        #pragma unroll
        for (int r = 0; r < WROWS; ++r) tr[r] = __shfl(tauF, r);
        float oac[WROWS];
        #pragma unroll
        for (int r = 0; r < WROWS; ++r) oac[r] = 0.f;
        const float* Vl = Vb + l;

        for (int i = 0; i < maxc; ++i) {
            #pragma unroll
            for (int r = 0; r < WROWS; ++r) {
                #pragma unroll
                for (int j = 0; j < 4; ++j) {
                    const unsigned int pk = s_pack[widx][i][r + 16 * j]; // bcast
                    const float val =
                        __builtin_bit_cast(float, pk & 0xFFFFF800u);
                    const float pp = fmaxf(val - tr[r], 0.f);  // 0 for sentinel
                    const int col = (int)(pk & 0x7FFu);
                    oac[r] = fmaf(pp, Vl[(size_t)col * DHEAD], oac[r]);
                }
            }
        }
        #pragma unroll
        for (int r = 0; r < WROWS; ++r)
            Of[(size_t)(row0w + r) * DHEAD + l] = oac[r] * 0.125f;
    } else {
        // ---- fallback: full-scan Michelot from t1 (cheap) + dense PV ----
        float tv = t1;
        int cprev = -1;
        for (int it = 0; it < 12; ++it) {
            float s = 0.f, c = 0.f;
            #pragma unroll 4
            for (int ct = 0; ct < S_LEN / 16; ++ct) {
                f32x4 a;
                SCORE_TILE(a, ct);
                #pragma unroll
                for (int e = 0; e < 4; ++e) {
                    const bool in = a[e] > tv;
                    s += in ? a[e] : 0.f;
                    c += in ? 1.f : 0.f;
                }
            }
            s += __shfl_xor(s, 16); c += __shfl_xor(c, 16);
            s += __shfl_xor(s, 32); c += __shfl_xor(c, 32);
            tv = (s - 8.f) / c;
            const int C = (int)c;
            const bool done = (C == cprev);
            cprev = C;
            if (__all(done ? 1 : 0)) break;
        }
        tauF = tv;

        // dense chunked PV via this wave's own 6 KB LDS chunk as [16][64]
        float* p_lds = reinterpret_cast<float*>(&s_pack[widx][0][0]);
        float ofb[WROWS];
        #pragma unroll
        for (int r = 0; r < WROWS; ++r) ofb[r] = 0.f;
        for (int cc = 0; cc < 32; ++cc) {
            #pragma unroll
            for (int tt = 0; tt < 4; ++tt) {
                f32x4 a;
                SCORE_TILE(a, cc * 4 + tt);
                #pragma unroll
                for (int e = 0; e < 4; ++e)
                    p_lds[lm * 64 + tt * 16 + lk * 4 + e] = fmaxf(a[e] - tauF, 0.f);
            }
            for (int c2 = 0; c2 < 64; ++c2) {
                const float vv = Vb[(size_t)(cc * 64 + c2) * DHEAD + l];
                #pragma unroll
                for (int r = 0; r < WROWS; ++r)
                    ofb[r] += p_lds[r * 64 + c2] * vv;
            }
        }
        #pragma unroll
        for (int r = 0; r < WROWS; ++r)
            Of[(size_t)(row0w + r) * DHEAD + l] = ofb[r] * 0.125f;
    }
    #undef SCORE_TILE
}

extern "C" void kernel_launch(void* const* d_in, const int* in_sizes, int n_in,
                              void* d_out, int out_size, void* d_ws, size_t ws_size,
                              hipStream_t stream) {
    const float* q = (const float*)d_in[0];
    const float* k = (const float*)d_in[1];
    const float* v = (const float*)d_in[2];
    float* out = (float*)d_out;

    const int nElem = in_sizes[0];                    // B*H*S*D = 4194304
    const int BH    = nElem / (S_LEN * DHEAD);

    unsigned short* ks = (unsigned short*)d_ws;
    const int nfrag = nElem / 8;
    kswz_kernel<<<(nfrag + 255) / 256, 256, 0, stream>>>(k, (uint4*)ks, nfrag);

    const int grid = BH * (S_LEN / (WROWS * BWAVES)); // 1024 blocks
    spx_main<<<grid, 256, 0, stream>>>(q, ks, v, out);
}